// Round 1
// baseline (1317.084 us; speedup 1.0000x reference)
//
#include <hip/hip_runtime.h>
#include <math.h>

#define TOKENS 8192
#define DDIM 1024
#define FDIM 4096
#define NEXP 8
#define CAP 8192          // max tokens per expert (top-2 distinct -> <= TOKENS)
#define BM 128
#define BN 128
#define BK 32

typedef __bf16 bf16x8 __attribute__((ext_vector_type(8)));
typedef float f32x4 __attribute__((ext_vector_type(4)));

__device__ __forceinline__ unsigned short f2bf(float f) {
  union { float f; unsigned int u; } v; v.f = f;
  unsigned int u = v.u;
  return (unsigned short)((u + 0x7FFFu + ((u >> 16) & 1u)) >> 16);
}
__device__ __forceinline__ float bf2f(unsigned short h) {
  union { unsigned int u; float f; } v; v.u = ((unsigned int)h) << 16;
  return v.f;
}

// ---------------- conversion kernels ----------------

__global__ void k_convert_x(const float* __restrict__ x, unsigned short* __restrict__ xb) {
  int i = (blockIdx.x * 256 + threadIdx.x) * 4;
  float4 v = *(const float4*)(x + i);
  ushort4 o;
  o.x = f2bf(v.x); o.y = f2bf(v.y); o.z = f2bf(v.z); o.w = f2bf(v.w);
  *(ushort4*)(xb + i) = o;
}

// in: [E][R][C] fp32 -> out: [E][C][R] bf16
__global__ void k_tconv(const float* __restrict__ in, unsigned short* __restrict__ out,
                        int R, int C) {
  __shared__ float tile[32][33];
  size_t mat = (size_t)R * C;
  const float* src = in + (size_t)blockIdx.z * mat;
  unsigned short* dst = out + (size_t)blockIdx.z * mat;
  int c0 = blockIdx.x * 32, r0 = blockIdx.y * 32;
  int t = threadIdx.x;
#pragma unroll
  for (int i = 0; i < 4; ++i) {
    int lin = t + i * 256;
    int r = lin >> 5, c = lin & 31;
    tile[r][c] = src[(size_t)(r0 + r) * C + (c0 + c)];
  }
  __syncthreads();
#pragma unroll
  for (int i = 0; i < 4; ++i) {
    int lin = t + i * 256;
    int cc = lin >> 5, rr = lin & 31;
    dst[(size_t)(c0 + cc) * R + (r0 + rr)] = f2bf(tile[rr][cc]);
  }
}

// ---------------- gating ----------------

__global__ void k_zero(int* __restrict__ counts) {
  if (threadIdx.x < NEXP) counts[threadIdx.x] = 0;
}

__global__ void k_gate(const float* __restrict__ x, const float* __restrict__ gw,
                       int* __restrict__ counts, int* __restrict__ tok_list,
                       float* __restrict__ wgt_list, int* __restrict__ tok_slot) {
  int wave = threadIdx.x >> 6, lane = threadIdx.x & 63;
  int t = blockIdx.x * 4 + wave;
  const float* xr = x + (size_t)t * DDIM;
  float acc[NEXP];
#pragma unroll
  for (int e = 0; e < NEXP; ++e) acc[e] = 0.f;
  for (int d = lane; d < DDIM; d += 64) {
    float xv = xr[d];
    const float* g = gw + d * NEXP;
#pragma unroll
    for (int e = 0; e < NEXP; ++e) acc[e] += xv * g[e];
  }
#pragma unroll
  for (int e = 0; e < NEXP; ++e) {
#pragma unroll
    for (int off = 32; off > 0; off >>= 1) acc[e] += __shfl_down(acc[e], off, 64);
  }
  if (lane == 0) {
    int e0 = 0; float v0 = acc[0];
#pragma unroll
    for (int e = 1; e < NEXP; ++e) if (acc[e] > v0) { v0 = acc[e]; e0 = e; }
    int e1 = -1; float v1 = -3.0e38f;
#pragma unroll
    for (int e = 0; e < NEXP; ++e) if (e != e0 && acc[e] > v1) { v1 = acc[e]; e1 = e; }
    float p1 = expf(v1 - v0);
    float s = 1.0f + p1;
    float w0 = 1.0f / s, w1 = p1 / s;
    int pos0 = atomicAdd(&counts[e0], 1);
    tok_list[e0 * CAP + pos0] = t;
    wgt_list[e0 * CAP + pos0] = w0;
    tok_slot[t * 2 + 0] = e0 * CAP + pos0;
    int pos1 = atomicAdd(&counts[e1], 1);
    tok_list[e1 * CAP + pos1] = t;
    wgt_list[e1 * CAP + pos1] = w1;
    tok_slot[t * 2 + 1] = e1 * CAP + pos1;
  }
}

__global__ void k_scan(const int* __restrict__ counts, int* __restrict__ bases) {
  if (threadIdx.x == 0) {
    int s = 0;
    for (int e = 0; e < NEXP; ++e) { bases[e] = s; s += counts[e]; }
  }
}

// ---------------- GEMM1: H = silu(X@wi0) * (X@wi1), gathered rows ----------------
// grid: (FDIM/BN=32, CAP/BM=64, NEXP)

__global__ __launch_bounds__(256, 2) void k_gemm1(
    const unsigned short* __restrict__ xb, const unsigned short* __restrict__ w0t,
    const unsigned short* __restrict__ w1t, const int* __restrict__ counts,
    const int* __restrict__ bases, const int* __restrict__ tok_list,
    unsigned short* __restrict__ H) {
  int e = blockIdx.z, mt = blockIdx.y, nt = blockIdx.x;
  int cnt = counts[e];
  int m0 = mt * BM;
  if (m0 >= cnt) return;
  int mv = min(BM, cnt - m0);
  int gbase = bases[e] + m0;

  __shared__ __align__(16) unsigned short As[BM * BK];
  __shared__ __align__(16) unsigned short B0s[BN * BK];
  __shared__ __align__(16) unsigned short B1s[BN * BK];
  __shared__ int toks[BM];

  int t = threadIdx.x;
  if (t < BM) toks[t] = tok_list[e * CAP + m0 + min(t, mv - 1)];
  __syncthreads();

  int wid = t >> 6, lane = t & 63;
  int wm = (wid >> 1) * 64, wn = (wid & 1) * 64;
  int fr = lane & 15, fq = lane >> 4;

  f32x4 acc0[4][4], acc1[4][4];
#pragma unroll
  for (int mi = 0; mi < 4; ++mi)
#pragma unroll
    for (int ni = 0; ni < 4; ++ni)
#pragma unroll
      for (int r = 0; r < 4; ++r) { acc0[mi][ni][r] = 0.f; acc1[mi][ni][r] = 0.f; }

  const unsigned short* b0p = w0t + ((size_t)e * FDIM + nt * BN) * DDIM;
  const unsigned short* b1p = w1t + ((size_t)e * FDIM + nt * BN) * DDIM;

  for (int kt = 0; kt < DDIM; kt += BK) {
#pragma unroll
    for (int i = 0; i < 2; ++i) {
      int c = t + i * 256;
      int m = c >> 2, kc = (c & 3) * 8;
      uint4 va = *(const uint4*)(xb + (size_t)toks[m] * DDIM + kt + kc);
      *(uint4*)(As + m * BK + kc) = va;
      uint4 v0 = *(const uint4*)(b0p + (size_t)m * DDIM + kt + kc);
      *(uint4*)(B0s + m * BK + kc) = v0;
      uint4 v1 = *(const uint4*)(b1p + (size_t)m * DDIM + kt + kc);
      *(uint4*)(B1s + m * BK + kc) = v1;
    }
    __syncthreads();
    bf16x8 a[4], b0[4], b1[4];
#pragma unroll
    for (int mi = 0; mi < 4; ++mi)
      a[mi] = *(const bf16x8*)(As + (wm + mi * 16 + fr) * BK + fq * 8);
#pragma unroll
    for (int ni = 0; ni < 4; ++ni) {
      b0[ni] = *(const bf16x8*)(B0s + (wn + ni * 16 + fr) * BK + fq * 8);
      b1[ni] = *(const bf16x8*)(B1s + (wn + ni * 16 + fr) * BK + fq * 8);
    }
#pragma unroll
    for (int mi = 0; mi < 4; ++mi)
#pragma unroll
      for (int ni = 0; ni < 4; ++ni) {
        acc0[mi][ni] = __builtin_amdgcn_mfma_f32_16x16x32_bf16(a[mi], b0[ni], acc0[mi][ni], 0, 0, 0);
        acc1[mi][ni] = __builtin_amdgcn_mfma_f32_16x16x32_bf16(a[mi], b1[ni], acc1[mi][ni], 0, 0, 0);
      }
    __syncthreads();
  }

  int n0 = nt * BN + wn;
#pragma unroll
  for (int mi = 0; mi < 4; ++mi) {
    int mloc = wm + mi * 16 + fq * 4;
#pragma unroll
    for (int ni = 0; ni < 4; ++ni) {
      int col = n0 + ni * 16 + fr;
#pragma unroll
      for (int r = 0; r < 4; ++r) {
        int mrow = mloc + r;
        if (mrow < mv) {
          float g = acc0[mi][ni][r];
          float hv = (g / (1.0f + expf(-g))) * acc1[mi][ni][r];
          H[(size_t)(gbase + mrow) * FDIM + col] = f2bf(hv);
        }
      }
    }
  }
}

// ---------------- GEMM2: O = H @ wo^T(stored [D][F]) ----------------
// grid: (DDIM/BN=8, CAP/BM=64, NEXP)

__global__ __launch_bounds__(256, 2) void k_gemm2(
    const unsigned short* __restrict__ H, const unsigned short* __restrict__ wot,
    const int* __restrict__ counts, const int* __restrict__ bases,
    unsigned short* __restrict__ O) {
  int e = blockIdx.z, mt = blockIdx.y, nt = blockIdx.x;
  int cnt = counts[e];
  int m0 = mt * BM;
  if (m0 >= cnt) return;
  int mv = min(BM, cnt - m0);
  int gbase = bases[e] + m0;

  __shared__ __align__(16) unsigned short As[BM * BK];
  __shared__ __align__(16) unsigned short Bs[BN * BK];

  int t = threadIdx.x;
  int wid = t >> 6, lane = t & 63;
  int wm = (wid >> 1) * 64, wn = (wid & 1) * 64;
  int fr = lane & 15, fq = lane >> 4;

  f32x4 acc[4][4];
#pragma unroll
  for (int mi = 0; mi < 4; ++mi)
#pragma unroll
    for (int ni = 0; ni < 4; ++ni)
#pragma unroll
      for (int r = 0; r < 4; ++r) acc[mi][ni][r] = 0.f;

  const unsigned short* bp = wot + ((size_t)e * DDIM + nt * BN) * FDIM;

  for (int kt = 0; kt < FDIM; kt += BK) {
#pragma unroll
    for (int i = 0; i < 2; ++i) {
      int c = t + i * 256;
      int m = c >> 2, kc = (c & 3) * 8;
      int arow = gbase + min(m, mv - 1);
      uint4 va = *(const uint4*)(H + (size_t)arow * FDIM + kt + kc);
      *(uint4*)(As + m * BK + kc) = va;
      uint4 vb = *(const uint4*)(bp + (size_t)m * FDIM + kt + kc);
      *(uint4*)(Bs + m * BK + kc) = vb;
    }
    __syncthreads();
    bf16x8 a[4], b[4];
#pragma unroll
    for (int mi = 0; mi < 4; ++mi)
      a[mi] = *(const bf16x8*)(As + (wm + mi * 16 + fr) * BK + fq * 8);
#pragma unroll
    for (int ni = 0; ni < 4; ++ni)
      b[ni] = *(const bf16x8*)(Bs + (wn + ni * 16 + fr) * BK + fq * 8);
#pragma unroll
    for (int mi = 0; mi < 4; ++mi)
#pragma unroll
      for (int ni = 0; ni < 4; ++ni)
        acc[mi][ni] = __builtin_amdgcn_mfma_f32_16x16x32_bf16(a[mi], b[ni], acc[mi][ni], 0, 0, 0);
    __syncthreads();
  }

  int n0 = nt * BN + wn;
#pragma unroll
  for (int mi = 0; mi < 4; ++mi) {
    int mloc = wm + mi * 16 + fq * 4;
#pragma unroll
    for (int ni = 0; ni < 4; ++ni) {
      int col = n0 + ni * 16 + fr;
#pragma unroll
      for (int r = 0; r < 4; ++r) {
        int mrow = mloc + r;
        if (mrow < mv)
          O[(size_t)(gbase + mrow) * DDIM + col] = f2bf(acc[mi][ni][r]);
      }
    }
  }
}

// ---------------- combine: out[t] = w0*O[g0] + w1*O[g1] ----------------

__global__ void k_combine(const unsigned short* __restrict__ O, const int* __restrict__ bases,
                          const int* __restrict__ tok_slot, const float* __restrict__ wgt_list,
                          float* __restrict__ out) {
  int t = blockIdx.x;
  int s0 = tok_slot[t * 2 + 0];
  int s1 = tok_slot[t * 2 + 1];
  int g0 = bases[s0 / CAP] + (s0 & (CAP - 1));
  int g1 = bases[s1 / CAP] + (s1 & (CAP - 1));
  float w0 = wgt_list[s0], w1 = wgt_list[s1];
  int d = threadIdx.x * 4;
  ushort4 a = *(const ushort4*)(O + (size_t)g0 * DDIM + d);
  ushort4 b = *(const ushort4*)(O + (size_t)g1 * DDIM + d);
  float4 r;
  r.x = w0 * bf2f(a.x) + w1 * bf2f(b.x);
  r.y = w0 * bf2f(a.y) + w1 * bf2f(b.y);
  r.z = w0 * bf2f(a.z) + w1 * bf2f(b.z);
  r.w = w0 * bf2f(a.w) + w1 * bf2f(b.w);
  *(float4*)(out + (size_t)t * DDIM + d) = r;
}

// ---------------- launch ----------------

extern "C" void kernel_launch(void* const* d_in, const int* in_sizes, int n_in,
                              void* d_out, int out_size, void* d_ws, size_t ws_size,
                              hipStream_t stream) {
  const float* x   = (const float*)d_in[0];
  const float* gw  = (const float*)d_in[1];
  const float* wi0 = (const float*)d_in[2];
  const float* wi1 = (const float*)d_in[3];
  const float* wo  = (const float*)d_in[4];
  float* out = (float*)d_out;

  char* p = (char*)d_ws;
  unsigned short* xb  = (unsigned short*)p; p += (size_t)TOKENS * DDIM * 2;          // 16 MB
  unsigned short* w0t = (unsigned short*)p; p += (size_t)NEXP * FDIM * DDIM * 2;     // 64 MB
  unsigned short* w1t = (unsigned short*)p; p += (size_t)NEXP * FDIM * DDIM * 2;     // 64 MB
  unsigned short* wot = (unsigned short*)p; p += (size_t)NEXP * DDIM * FDIM * 2;     // 64 MB
  unsigned short* H   = (unsigned short*)p; p += (size_t)2 * TOKENS * FDIM * 2;      // 128 MB
  unsigned short* O   = (unsigned short*)p; p += (size_t)2 * TOKENS * DDIM * 2;      // 32 MB
  int*   counts   = (int*)p; p += 256;
  int*   bases    = (int*)p; p += 256;
  int*   tok_list = (int*)p; p += (size_t)NEXP * CAP * 4;
  float* wgt_list = (float*)p; p += (size_t)NEXP * CAP * 4;
  int*   tok_slot = (int*)p; p += (size_t)TOKENS * 2 * 4;

  // conversions
  k_convert_x<<<(TOKENS * DDIM) / 1024, 256, 0, stream>>>(x, xb);
  k_tconv<<<dim3(FDIM / 32, DDIM / 32, NEXP), 256, 0, stream>>>(wi0, w0t, DDIM, FDIM);
  k_tconv<<<dim3(FDIM / 32, DDIM / 32, NEXP), 256, 0, stream>>>(wi1, w1t, DDIM, FDIM);
  k_tconv<<<dim3(DDIM / 32, FDIM / 32, NEXP), 256, 0, stream>>>(wo, wot, FDIM, DDIM);

  // gating + routing
  k_zero<<<1, 64, 0, stream>>>(counts);
  k_gate<<<TOKENS / 4, 256, 0, stream>>>(x, gw, counts, tok_list, wgt_list, tok_slot);
  k_scan<<<1, 64, 0, stream>>>(counts, bases);

  // expert MLP
  k_gemm1<<<dim3(FDIM / BN, CAP / BM, NEXP), 256, 0, stream>>>(xb, w0t, w1t, counts, bases, tok_list, H);
  k_gemm2<<<dim3(DDIM / BN, CAP / BM, NEXP), 256, 0, stream>>>(H, wot, counts, bases, O);

  // weighted combine
  k_combine<<<TOKENS, 256, 0, stream>>>(O, bases, tok_slot, wgt_list, out);
}

// Round 2
// 1266.578 us; speedup vs baseline: 1.0399x; 1.0399x over previous
//
#include <hip/hip_runtime.h>
#include <math.h>

#define TOKENS 8192
#define DDIM 1024
#define FDIM 4096
#define NEXP 8
#define CAP 8192
#define BM 128
#define BN 128
#define BK 32

typedef __bf16 bf16x8 __attribute__((ext_vector_type(8)));
typedef float f32x4 __attribute__((ext_vector_type(4)));

__device__ __forceinline__ unsigned short f2bf(float f) {
  union { float f; unsigned int u; } v; v.f = f;
  unsigned int u = v.u;
  return (unsigned short)((u + 0x7FFFu + ((u >> 16) & 1u)) >> 16);
}
__device__ __forceinline__ float bf2f(unsigned short h) {
  union { unsigned int u; float f; } v; v.u = ((unsigned int)h) << 16;
  return v.f;
}

// async global->LDS, 16 bytes per lane. LDS dest must be wave-uniform base + lane*16.
__device__ __forceinline__ void load_lds16(const void* g, void* l) {
  __builtin_amdgcn_global_load_lds(
      (const __attribute__((address_space(1))) void*)g,
      (__attribute__((address_space(3))) void*)l, 16, 0, 0);
}

// ---------------- conversion kernels ----------------

__global__ void k_convert_x(const float* __restrict__ x, unsigned short* __restrict__ xb) {
  int i = (blockIdx.x * 256 + threadIdx.x) * 4;
  float4 v = *(const float4*)(x + i);
  ushort4 o;
  o.x = f2bf(v.x); o.y = f2bf(v.y); o.z = f2bf(v.z); o.w = f2bf(v.w);
  *(ushort4*)(xb + i) = o;
}

// in: [E][R][C] fp32 -> out: [E][C][R] bf16. Tile 32 rows x 128 cols, float4 in / ushort4 out.
__global__ void k_tconv(const float* __restrict__ in, unsigned short* __restrict__ out,
                        int R, int C) {
  __shared__ float tile[32][132];
  size_t mat = (size_t)R * C;
  const float* src = in + (size_t)blockIdx.z * mat;
  unsigned short* dst = out + (size_t)blockIdx.z * mat;
  int c0 = blockIdx.x * 128, r0 = blockIdx.y * 32;
  int t = threadIdx.x;
#pragma unroll
  for (int i = 0; i < 4; ++i) {
    int idx = i * 1024 + t * 4;
    int r = idx >> 7, c = idx & 127;
    float4 v = *(const float4*)(src + (size_t)(r0 + r) * C + (c0 + c));
    *(float4*)&tile[r][c] = v;
  }
  __syncthreads();
#pragma unroll
  for (int i = 0; i < 4; ++i) {
    int idx = i * 1024 + t * 4;
    int c = idx >> 5, r = idx & 31;   // r in {0,4,...,28}
    ushort4 o;
    o.x = f2bf(tile[r + 0][c]);
    o.y = f2bf(tile[r + 1][c]);
    o.z = f2bf(tile[r + 2][c]);
    o.w = f2bf(tile[r + 3][c]);
    *(ushort4*)(dst + (size_t)(c0 + c) * R + (r0 + r)) = o;
  }
}

// ---------------- gating ----------------

__global__ void k_zero(int* __restrict__ counts) {
  if (threadIdx.x < NEXP) counts[threadIdx.x] = 0;
}

__global__ void k_gate(const float* __restrict__ x, const float* __restrict__ gw,
                       int* __restrict__ counts, int* __restrict__ tok_list,
                       float* __restrict__ wgt_list, int* __restrict__ tok_slot) {
  int wave = threadIdx.x >> 6, lane = threadIdx.x & 63;
  int t = blockIdx.x * 4 + wave;
  const float* xr = x + (size_t)t * DDIM;
  float acc[NEXP];
#pragma unroll
  for (int e = 0; e < NEXP; ++e) acc[e] = 0.f;
  for (int d = lane; d < DDIM; d += 64) {
    float xv = xr[d];
    const float* g = gw + d * NEXP;
#pragma unroll
    for (int e = 0; e < NEXP; ++e) acc[e] += xv * g[e];
  }
#pragma unroll
  for (int e = 0; e < NEXP; ++e) {
#pragma unroll
    for (int off = 32; off > 0; off >>= 1) acc[e] += __shfl_down(acc[e], off, 64);
  }
  if (lane == 0) {
    int e0 = 0; float v0 = acc[0];
#pragma unroll
    for (int e = 1; e < NEXP; ++e) if (acc[e] > v0) { v0 = acc[e]; e0 = e; }
    int e1 = -1; float v1 = -3.0e38f;
#pragma unroll
    for (int e = 0; e < NEXP; ++e) if (e != e0 && acc[e] > v1) { v1 = acc[e]; e1 = e; }
    float p1 = expf(v1 - v0);
    float s = 1.0f + p1;
    float w0 = 1.0f / s, w1 = p1 / s;
    int pos0 = atomicAdd(&counts[e0], 1);
    tok_list[e0 * CAP + pos0] = t;
    wgt_list[e0 * CAP + pos0] = w0;
    tok_slot[t * 2 + 0] = e0 * CAP + pos0;
    int pos1 = atomicAdd(&counts[e1], 1);
    tok_list[e1 * CAP + pos1] = t;
    wgt_list[e1 * CAP + pos1] = w1;
    tok_slot[t * 2 + 1] = e1 * CAP + pos1;
  }
}

__global__ void k_scan(const int* __restrict__ counts, int* __restrict__ bases) {
  if (threadIdx.x == 0) {
    int s = 0;
    for (int e = 0; e < NEXP; ++e) { bases[e] = s; s += counts[e]; }
  }
}

// ---------------- GEMM1: H = silu(X@wi0) * (X@wi1), gathered rows ----------------
// LDS chunk swizzle: logical k-chunk fq of row stored at chunk cs = fq ^ ((row>>1)&3).
// grid: (FDIM/BN=32, CAP/BM=64, NEXP)

__global__ __launch_bounds__(256, 2) void k_gemm1(
    const unsigned short* __restrict__ xb, const unsigned short* __restrict__ w0t,
    const unsigned short* __restrict__ w1t, const int* __restrict__ counts,
    const int* __restrict__ bases, const int* __restrict__ tok_list,
    unsigned short* __restrict__ H) {
  int e = blockIdx.z, mt = blockIdx.y, nt = blockIdx.x;
  int cnt = counts[e];
  int m0 = mt * BM;
  if (m0 >= cnt) return;
  int mv = min(BM, cnt - m0);
  int gbase = bases[e] + m0;

  __shared__ __align__(16) unsigned short As[BM * BK];
  __shared__ __align__(16) unsigned short B0s[BN * BK];
  __shared__ __align__(16) unsigned short B1s[BN * BK];
  __shared__ int toks[BM];

  int t = threadIdx.x;
  if (t < BM) toks[t] = tok_list[e * CAP + m0 + min(t, mv - 1)];
  __syncthreads();

  int wid = t >> 6, lane = t & 63;
  int wm = (wid >> 1) * 64, wn = (wid & 1) * 64;
  int fr = lane & 15, fq = lane >> 4;
  int csl = fq ^ ((fr >> 1) & 3);   // swizzled chunk index for fragment reads (lane-const)

  // staging slot -> (row, global k-chunk)
  int row0 = t >> 2,        row1 = (t + 256) >> 2;
  int fq0 = (t & 3) ^ ((row0 >> 1) & 3);
  int fq1 = ((t + 256) & 3) ^ ((row1 >> 1) & 3);

  f32x4 acc0[4][4], acc1[4][4];
#pragma unroll
  for (int mi = 0; mi < 4; ++mi)
#pragma unroll
    for (int ni = 0; ni < 4; ++ni)
#pragma unroll
      for (int r = 0; r < 4; ++r) { acc0[mi][ni][r] = 0.f; acc1[mi][ni][r] = 0.f; }

  const unsigned short* b0p = w0t + ((size_t)e * FDIM + nt * BN) * DDIM;
  const unsigned short* b1p = w1t + ((size_t)e * FDIM + nt * BN) * DDIM;
  const size_t arow0 = (size_t)toks[row0] * DDIM;
  const size_t arow1 = (size_t)toks[row1] * DDIM;

  for (int kt = 0; kt < DDIM; kt += BK) {
    load_lds16(xb + arow0 + kt + fq0 * 8, As + t * 8);
    load_lds16(xb + arow1 + kt + fq1 * 8, As + (t + 256) * 8);
    load_lds16(b0p + (size_t)row0 * DDIM + kt + fq0 * 8, B0s + t * 8);
    load_lds16(b0p + (size_t)row1 * DDIM + kt + fq1 * 8, B0s + (t + 256) * 8);
    load_lds16(b1p + (size_t)row0 * DDIM + kt + fq0 * 8, B1s + t * 8);
    load_lds16(b1p + (size_t)row1 * DDIM + kt + fq1 * 8, B1s + (t + 256) * 8);
    __syncthreads();
    bf16x8 a[4], b0[4], b1[4];
#pragma unroll
    for (int mi = 0; mi < 4; ++mi)
      a[mi] = *(const bf16x8*)(As + (wm + mi * 16 + fr) * BK + csl * 8);
#pragma unroll
    for (int ni = 0; ni < 4; ++ni) {
      b0[ni] = *(const bf16x8*)(B0s + (wn + ni * 16 + fr) * BK + csl * 8);
      b1[ni] = *(const bf16x8*)(B1s + (wn + ni * 16 + fr) * BK + csl * 8);
    }
#pragma unroll
    for (int mi = 0; mi < 4; ++mi)
#pragma unroll
      for (int ni = 0; ni < 4; ++ni) {
        acc0[mi][ni] = __builtin_amdgcn_mfma_f32_16x16x32_bf16(a[mi], b0[ni], acc0[mi][ni], 0, 0, 0);
        acc1[mi][ni] = __builtin_amdgcn_mfma_f32_16x16x32_bf16(a[mi], b1[ni], acc1[mi][ni], 0, 0, 0);
      }
    __syncthreads();
  }

  int n0 = nt * BN + wn;
#pragma unroll
  for (int mi = 0; mi < 4; ++mi) {
    int mloc = wm + mi * 16 + fq * 4;
#pragma unroll
    for (int ni = 0; ni < 4; ++ni) {
      int col = n0 + ni * 16 + fr;
#pragma unroll
      for (int r = 0; r < 4; ++r) {
        int mrow = mloc + r;
        if (mrow < mv) {
          float g = acc0[mi][ni][r];
          float hv = (g / (1.0f + expf(-g))) * acc1[mi][ni][r];
          H[(size_t)(gbase + mrow) * FDIM + col] = f2bf(hv);
        }
      }
    }
  }
}

// ---------------- GEMM2: O = H @ wo^T(stored [D][F]) ----------------
// grid: (DDIM/BN=8, CAP/BM=64, NEXP)

__global__ __launch_bounds__(256, 2) void k_gemm2(
    const unsigned short* __restrict__ H, const unsigned short* __restrict__ wot,
    const int* __restrict__ counts, const int* __restrict__ bases,
    unsigned short* __restrict__ O) {
  int e = blockIdx.z, mt = blockIdx.y, nt = blockIdx.x;
  int cnt = counts[e];
  int m0 = mt * BM;
  if (m0 >= cnt) return;
  int mv = min(BM, cnt - m0);
  int gbase = bases[e] + m0;

  __shared__ __align__(16) unsigned short As[BM * BK];
  __shared__ __align__(16) unsigned short Bs[BN * BK];

  int t = threadIdx.x;
  int wid = t >> 6, lane = t & 63;
  int wm = (wid >> 1) * 64, wn = (wid & 1) * 64;
  int fr = lane & 15, fq = lane >> 4;
  int csl = fq ^ ((fr >> 1) & 3);

  int row0 = t >> 2,        row1 = (t + 256) >> 2;
  int fq0 = (t & 3) ^ ((row0 >> 1) & 3);
  int fq1 = ((t + 256) & 3) ^ ((row1 >> 1) & 3);

  f32x4 acc[4][4];
#pragma unroll
  for (int mi = 0; mi < 4; ++mi)
#pragma unroll
    for (int ni = 0; ni < 4; ++ni)
#pragma unroll
      for (int r = 0; r < 4; ++r) acc[mi][ni][r] = 0.f;

  const unsigned short* bp = wot + ((size_t)e * DDIM + nt * BN) * FDIM;
  const size_t arow0 = (size_t)(gbase + min(row0, mv - 1)) * FDIM;
  const size_t arow1 = (size_t)(gbase + min(row1, mv - 1)) * FDIM;

  for (int kt = 0; kt < FDIM; kt += BK) {
    load_lds16(H + arow0 + kt + fq0 * 8, As + t * 8);
    load_lds16(H + arow1 + kt + fq1 * 8, As + (t + 256) * 8);
    load_lds16(bp + (size_t)row0 * FDIM + kt + fq0 * 8, Bs + t * 8);
    load_lds16(bp + (size_t)row1 * FDIM + kt + fq1 * 8, Bs + (t + 256) * 8);
    __syncthreads();
    bf16x8 a[4], b[4];
#pragma unroll
    for (int mi = 0; mi < 4; ++mi)
      a[mi] = *(const bf16x8*)(As + (wm + mi * 16 + fr) * BK + csl * 8);
#pragma unroll
    for (int ni = 0; ni < 4; ++ni)
      b[ni] = *(const bf16x8*)(Bs + (wn + ni * 16 + fr) * BK + csl * 8);
#pragma unroll
    for (int mi = 0; mi < 4; ++mi)
#pragma unroll
      for (int ni = 0; ni < 4; ++ni)
        acc[mi][ni] = __builtin_amdgcn_mfma_f32_16x16x32_bf16(a[mi], b[ni], acc[mi][ni], 0, 0, 0);
    __syncthreads();
  }

  int n0 = nt * BN + wn;
#pragma unroll
  for (int mi = 0; mi < 4; ++mi) {
    int mloc = wm + mi * 16 + fq * 4;
#pragma unroll
    for (int ni = 0; ni < 4; ++ni) {
      int col = n0 + ni * 16 + fr;
#pragma unroll
      for (int r = 0; r < 4; ++r) {
        int mrow = mloc + r;
        if (mrow < mv)
          O[(size_t)(gbase + mrow) * DDIM + col] = f2bf(acc[mi][ni][r]);
      }
    }
  }
}

// ---------------- combine: out[t] = w0*O[g0] + w1*O[g1] ----------------

__global__ void k_combine(const unsigned short* __restrict__ O, const int* __restrict__ bases,
                          const int* __restrict__ tok_slot, const float* __restrict__ wgt_list,
                          float* __restrict__ out) {
  int t = blockIdx.x;
  int s0 = tok_slot[t * 2 + 0];
  int s1 = tok_slot[t * 2 + 1];
  int g0 = bases[s0 / CAP] + (s0 & (CAP - 1));
  int g1 = bases[s1 / CAP] + (s1 & (CAP - 1));
  float w0 = wgt_list[s0], w1 = wgt_list[s1];
  int d = threadIdx.x * 4;
  ushort4 a = *(const ushort4*)(O + (size_t)g0 * DDIM + d);
  ushort4 b = *(const ushort4*)(O + (size_t)g1 * DDIM + d);
  float4 r;
  r.x = w0 * bf2f(a.x) + w1 * bf2f(b.x);
  r.y = w0 * bf2f(a.y) + w1 * bf2f(b.y);
  r.z = w0 * bf2f(a.z) + w1 * bf2f(b.z);
  r.w = w0 * bf2f(a.w) + w1 * bf2f(b.w);
  *(float4*)(out + (size_t)t * DDIM + d) = r;
}

// ---------------- launch ----------------

extern "C" void kernel_launch(void* const* d_in, const int* in_sizes, int n_in,
                              void* d_out, int out_size, void* d_ws, size_t ws_size,
                              hipStream_t stream) {
  const float* x   = (const float*)d_in[0];
  const float* gw  = (const float*)d_in[1];
  const float* wi0 = (const float*)d_in[2];
  const float* wi1 = (const float*)d_in[3];
  const float* wo  = (const float*)d_in[4];
  float* out = (float*)d_out;

  char* p = (char*)d_ws;
  unsigned short* xb  = (unsigned short*)p; p += (size_t)TOKENS * DDIM * 2;          // 16 MB
  unsigned short* w0t = (unsigned short*)p; p += (size_t)NEXP * FDIM * DDIM * 2;     // 64 MB
  unsigned short* w1t = (unsigned short*)p; p += (size_t)NEXP * FDIM * DDIM * 2;     // 64 MB
  unsigned short* wot = (unsigned short*)p; p += (size_t)NEXP * DDIM * FDIM * 2;     // 64 MB
  unsigned short* H   = (unsigned short*)p; p += (size_t)2 * TOKENS * FDIM * 2;      // 128 MB
  unsigned short* O   = (unsigned short*)p; p += (size_t)2 * TOKENS * DDIM * 2;      // 32 MB
  int*   counts   = (int*)p; p += 256;
  int*   bases    = (int*)p; p += 256;
  int*   tok_list = (int*)p; p += (size_t)NEXP * CAP * 4;
  float* wgt_list = (float*)p; p += (size_t)NEXP * CAP * 4;
  int*   tok_slot = (int*)p; p += (size_t)TOKENS * 2 * 4;

  // conversions
  k_convert_x<<<(TOKENS * DDIM) / 1024, 256, 0, stream>>>(x, xb);
  k_tconv<<<dim3(FDIM / 128, DDIM / 32, NEXP), 256, 0, stream>>>(wi0, w0t, DDIM, FDIM);
  k_tconv<<<dim3(FDIM / 128, DDIM / 32, NEXP), 256, 0, stream>>>(wi1, w1t, DDIM, FDIM);
  k_tconv<<<dim3(DDIM / 128, FDIM / 32, NEXP), 256, 0, stream>>>(wo, wot, FDIM, DDIM);

  // gating + routing
  k_zero<<<1, 64, 0, stream>>>(counts);
  k_gate<<<TOKENS / 4, 256, 0, stream>>>(x, gw, counts, tok_list, wgt_list, tok_slot);
  k_scan<<<1, 64, 0, stream>>>(counts, bases);

  // expert MLP
  k_gemm1<<<dim3(FDIM / BN, CAP / BM, NEXP), 256, 0, stream>>>(xb, w0t, w1t, counts, bases, tok_list, H);
  k_gemm2<<<dim3(DDIM / BN, CAP / BM, NEXP), 256, 0, stream>>>(H, wot, counts, bases, O);

  // weighted combine
  k_combine<<<TOKENS, 256, 0, stream>>>(O, bases, tok_slot, wgt_list, out);
}

// Round 3
// 1159.473 us; speedup vs baseline: 1.1359x; 1.0924x over previous
//
#include <hip/hip_runtime.h>
#include <math.h>

#define TOKENS 8192
#define DDIM 1024
#define FDIM 4096
#define NEXP 8
#define CAP 8192
#define BM 128
#define BN 128
#define BK 64   // 8 chunks of 16B per row

typedef __bf16 bf16x8 __attribute__((ext_vector_type(8)));
typedef float f32x4 __attribute__((ext_vector_type(4)));

__device__ __forceinline__ unsigned short f2bf(float f) {
  union { float f; unsigned int u; } v; v.f = f;
  unsigned int u = v.u;
  return (unsigned short)((u + 0x7FFFu + ((u >> 16) & 1u)) >> 16);
}
__device__ __forceinline__ float bf2f(unsigned short h) {
  union { unsigned int u; float f; } v; v.u = ((unsigned int)h) << 16;
  return v.f;
}

__device__ __forceinline__ void load_lds16(const void* g, void* l) {
  __builtin_amdgcn_global_load_lds(
      (const __attribute__((address_space(1))) void*)g,
      (__attribute__((address_space(3))) void*)l, 16, 0, 0);
}

// ---------------- weight transpose+convert: [E][R][C] fp32 -> [E][C][R] bf16 ----------------
__global__ void k_tconv(const float* __restrict__ in, unsigned short* __restrict__ out,
                        int R, int C) {
  __shared__ float tile[32][132];
  size_t mat = (size_t)R * C;
  const float* src = in + (size_t)blockIdx.z * mat;
  unsigned short* dst = out + (size_t)blockIdx.z * mat;
  int c0 = blockIdx.x * 128, r0 = blockIdx.y * 32;
  int t = threadIdx.x;
#pragma unroll
  for (int i = 0; i < 4; ++i) {
    int idx = i * 1024 + t * 4;
    int r = idx >> 7, c = idx & 127;
    float4 v = *(const float4*)(src + (size_t)(r0 + r) * C + (c0 + c));
    *(float4*)&tile[r][c] = v;
  }
  __syncthreads();
#pragma unroll
  for (int i = 0; i < 4; ++i) {
    int idx = i * 1024 + t * 4;
    int c = idx >> 5, r = idx & 31;
    ushort4 o;
    o.x = f2bf(tile[r + 0][c]);
    o.y = f2bf(tile[r + 1][c]);
    o.z = f2bf(tile[r + 2][c]);
    o.w = f2bf(tile[r + 3][c]);
    *(ushort4*)(dst + (size_t)(c0 + c) * R + (r0 + r)) = o;
  }
}

// ---------------- gating (also emits xb = bf16(x)) ----------------

__global__ void k_zero(int* __restrict__ counts) {
  if (threadIdx.x < NEXP) counts[threadIdx.x] = 0;
}

__global__ void k_gate(const float* __restrict__ x, const float* __restrict__ gw,
                       unsigned short* __restrict__ xb,
                       int* __restrict__ counts, int* __restrict__ tok_list,
                       float* __restrict__ wgt_list, int* __restrict__ tok_slot) {
  int wave = threadIdx.x >> 6, lane = threadIdx.x & 63;
  int t = blockIdx.x * 4 + wave;
  const float* xr = x + (size_t)t * DDIM;
  unsigned short* xbr = xb + (size_t)t * DDIM;
  float acc[NEXP];
#pragma unroll
  for (int e = 0; e < NEXP; ++e) acc[e] = 0.f;
  for (int d = lane; d < DDIM; d += 64) {
    float xv = xr[d];
    xbr[d] = f2bf(xv);
    const float* g = gw + d * NEXP;
#pragma unroll
    for (int e = 0; e < NEXP; ++e) acc[e] += xv * g[e];
  }
#pragma unroll
  for (int e = 0; e < NEXP; ++e) {
#pragma unroll
    for (int off = 32; off > 0; off >>= 1) acc[e] += __shfl_down(acc[e], off, 64);
  }
  if (lane == 0) {
    int e0 = 0; float v0 = acc[0];
#pragma unroll
    for (int e = 1; e < NEXP; ++e) if (acc[e] > v0) { v0 = acc[e]; e0 = e; }
    int e1 = -1; float v1 = -3.0e38f;
#pragma unroll
    for (int e = 0; e < NEXP; ++e) if (e != e0 && acc[e] > v1) { v1 = acc[e]; e1 = e; }
    float p1 = expf(v1 - v0);
    float s = 1.0f + p1;
    float w0 = 1.0f / s, w1 = p1 / s;
    int pos0 = atomicAdd(&counts[e0], 1);
    tok_list[e0 * CAP + pos0] = t;
    wgt_list[e0 * CAP + pos0] = w0;
    tok_slot[t * 2 + 0] = e0 * CAP + pos0;
    int pos1 = atomicAdd(&counts[e1], 1);
    tok_list[e1 * CAP + pos1] = t;
    wgt_list[e1 * CAP + pos1] = w1;
    tok_slot[t * 2 + 1] = e1 * CAP + pos1;
  }
}

__global__ void k_scan(const int* __restrict__ counts, int* __restrict__ bases) {
  if (threadIdx.x == 0) {
    int s = 0;
    for (int e = 0; e < NEXP; ++e) { bases[e] = s; s += counts[e]; }
  }
}

// LDS layout (per tile, BK=64): row stride 64 ushorts (128 B); logical 16B-chunk c of
// row r stored at position c ^ (r & 7).  Staging slot s (0..1023): row=s>>3, pos=s&7,
// logical chunk = (s&7) ^ (row&7).  Fragment read (16x16x32 step kh, lane fr,fq):
// addr = row*64 + (((kh<<2)|fq) ^ (fr&7))*8  [ushort units]; row&7 == fr&7 (wm,mi*16 mult of 8).

// ---------------- GEMM1: H = silu(X@wi0) * (X@wi1) ----------------
// 1D grid 16384; XCD-aware decode groups 8 nt-blocks (same e,mt) per XCD.

__global__ __launch_bounds__(256, 2) void k_gemm1(
    const unsigned short* __restrict__ xb, const unsigned short* __restrict__ w0t,
    const unsigned short* __restrict__ w1t, const int* __restrict__ counts,
    const int* __restrict__ bases, const int* __restrict__ tok_list,
    unsigned short* __restrict__ H) {
  int b = blockIdx.x;
  int xcd = b & 7, j = b >> 3;
  int i8 = j & 7, grp = j >> 3;        // grp 0..255
  int G = grp * 8 + xcd;               // 0..2047
  int e = G >> 8;
  int mt = (G >> 2) & 63;
  int nt = ((G & 3) << 3) | i8;        // 0..31

  int cnt = counts[e];
  int m0 = mt * BM;
  if (m0 >= cnt) return;
  int mv = min(BM, cnt - m0);
  int gbase = bases[e] + m0;

  __shared__ __align__(16) unsigned short As[BM * BK];
  __shared__ __align__(16) unsigned short B0s[BN * BK];
  __shared__ __align__(16) unsigned short B1s[BN * BK];
  __shared__ int toks[BM];

  int t = threadIdx.x;
  if (t < BM) toks[t] = tok_list[e * CAP + m0 + min(t, mv - 1)];
  __syncthreads();

  int wid = t >> 6, lane = t & 63;
  int wm = (wid >> 1) * 64, wn = (wid & 1) * 64;
  int fr = lane & 15, fq = lane >> 4;
  int sw = fr & 7;                     // lane-const swizzle key
  int co0 = (fq ^ sw) * 8;             // kh=0 chunk offset (ushorts)
  int co1 = ((4 | fq) ^ sw) * 8;       // kh=1

  // staging: 4 rounds per tile
  int srow[4], soff[4];
#pragma unroll
  for (int r = 0; r < 4; ++r) {
    int s = t + r * 256;
    srow[r] = s >> 3;
    soff[r] = ((s & 7) ^ (srow[r] & 7)) * 8;   // element offset within row
  }
  size_t arow[4];
#pragma unroll
  for (int r = 0; r < 4; ++r) arow[r] = (size_t)toks[srow[r]] * DDIM + soff[r];

  f32x4 acc0[4][4], acc1[4][4];
#pragma unroll
  for (int mi = 0; mi < 4; ++mi)
#pragma unroll
    for (int ni = 0; ni < 4; ++ni)
#pragma unroll
      for (int r = 0; r < 4; ++r) { acc0[mi][ni][r] = 0.f; acc1[mi][ni][r] = 0.f; }

  const unsigned short* b0p = w0t + ((size_t)e * FDIM + nt * BN) * DDIM;
  const unsigned short* b1p = w1t + ((size_t)e * FDIM + nt * BN) * DDIM;

  for (int kt = 0; kt < DDIM; kt += BK) {
#pragma unroll
    for (int r = 0; r < 4; ++r) {
      int s = t + r * 256;
      load_lds16(xb + arow[r] + kt, As + s * 8);
      load_lds16(b0p + (size_t)srow[r] * DDIM + soff[r] + kt, B0s + s * 8);
      load_lds16(b1p + (size_t)srow[r] * DDIM + soff[r] + kt, B1s + s * 8);
    }
    __syncthreads();
#pragma unroll
    for (int kh = 0; kh < 2; ++kh) {
      int co = kh ? co1 : co0;
      bf16x8 a[4], b0[4], b1[4];
#pragma unroll
      for (int mi = 0; mi < 4; ++mi)
        a[mi] = *(const bf16x8*)(As + (wm + mi * 16 + fr) * BK + co);
#pragma unroll
      for (int ni = 0; ni < 4; ++ni) {
        b0[ni] = *(const bf16x8*)(B0s + (wn + ni * 16 + fr) * BK + co);
        b1[ni] = *(const bf16x8*)(B1s + (wn + ni * 16 + fr) * BK + co);
      }
#pragma unroll
      for (int mi = 0; mi < 4; ++mi)
#pragma unroll
        for (int ni = 0; ni < 4; ++ni) {
          acc0[mi][ni] = __builtin_amdgcn_mfma_f32_16x16x32_bf16(a[mi], b0[ni], acc0[mi][ni], 0, 0, 0);
          acc1[mi][ni] = __builtin_amdgcn_mfma_f32_16x16x32_bf16(a[mi], b1[ni], acc1[mi][ni], 0, 0, 0);
        }
    }
    __syncthreads();
  }

  int n0 = nt * BN + wn;
#pragma unroll
  for (int mi = 0; mi < 4; ++mi) {
    int mloc = wm + mi * 16 + fq * 4;
#pragma unroll
    for (int ni = 0; ni < 4; ++ni) {
      int col = n0 + ni * 16 + fr;
#pragma unroll
      for (int r = 0; r < 4; ++r) {
        int mrow = mloc + r;
        if (mrow < mv) {
          float g = acc0[mi][ni][r];
          float hv = (g / (1.0f + expf(-g))) * acc1[mi][ni][r];
          H[(size_t)(gbase + mrow) * FDIM + col] = f2bf(hv);
        }
      }
    }
  }
}

// ---------------- GEMM2: O = H @ wo^T(stored [D][F]) ----------------
// 1D grid 4096; 8 nt-blocks (same e,mt -> same 1MB H-slab) per XCD.

__global__ __launch_bounds__(256, 2) void k_gemm2(
    const unsigned short* __restrict__ H, const unsigned short* __restrict__ wot,
    const int* __restrict__ counts, const int* __restrict__ bases,
    unsigned short* __restrict__ O) {
  int b = blockIdx.x;
  int xcd = b & 7, j = b >> 3;
  int i8 = j & 7, grp = j >> 3;        // grp 0..63
  int G = grp * 8 + xcd;               // 0..511
  int e = G >> 6;
  int mt = G & 63;
  int nt = i8;                         // 0..7

  int cnt = counts[e];
  int m0 = mt * BM;
  if (m0 >= cnt) return;
  int mv = min(BM, cnt - m0);
  int gbase = bases[e] + m0;

  __shared__ __align__(16) unsigned short As[BM * BK];
  __shared__ __align__(16) unsigned short Bs[BN * BK];

  int t = threadIdx.x;
  int wid = t >> 6, lane = t & 63;
  int wm = (wid >> 1) * 64, wn = (wid & 1) * 64;
  int fr = lane & 15, fq = lane >> 4;
  int sw = fr & 7;
  int co0 = (fq ^ sw) * 8;
  int co1 = ((4 | fq) ^ sw) * 8;

  int srow[4], soff[4];
#pragma unroll
  for (int r = 0; r < 4; ++r) {
    int s = t + r * 256;
    srow[r] = s >> 3;
    soff[r] = ((s & 7) ^ (srow[r] & 7)) * 8;
  }
  size_t arow[4];
#pragma unroll
  for (int r = 0; r < 4; ++r)
    arow[r] = (size_t)(gbase + min(srow[r], mv - 1)) * FDIM + soff[r];

  f32x4 acc[4][4];
#pragma unroll
  for (int mi = 0; mi < 4; ++mi)
#pragma unroll
    for (int ni = 0; ni < 4; ++ni)
#pragma unroll
      for (int r = 0; r < 4; ++r) acc[mi][ni][r] = 0.f;

  const unsigned short* bp = wot + ((size_t)e * DDIM + nt * BN) * FDIM;

  for (int kt = 0; kt < FDIM; kt += BK) {
#pragma unroll
    for (int r = 0; r < 4; ++r) {
      int s = t + r * 256;
      load_lds16(H + arow[r] + kt, As + s * 8);
      load_lds16(bp + (size_t)srow[r] * FDIM + soff[r] + kt, Bs + s * 8);
    }
    __syncthreads();
#pragma unroll
    for (int kh = 0; kh < 2; ++kh) {
      int co = kh ? co1 : co0;
      bf16x8 a[4], bb[4];
#pragma unroll
      for (int mi = 0; mi < 4; ++mi)
        a[mi] = *(const bf16x8*)(As + (wm + mi * 16 + fr) * BK + co);
#pragma unroll
      for (int ni = 0; ni < 4; ++ni)
        bb[ni] = *(const bf16x8*)(Bs + (wn + ni * 16 + fr) * BK + co);
#pragma unroll
      for (int mi = 0; mi < 4; ++mi)
#pragma unroll
        for (int ni = 0; ni < 4; ++ni)
          acc[mi][ni] = __builtin_amdgcn_mfma_f32_16x16x32_bf16(a[mi], bb[ni], acc[mi][ni], 0, 0, 0);
    }
    __syncthreads();
  }

  int n0 = nt * BN + wn;
#pragma unroll
  for (int mi = 0; mi < 4; ++mi) {
    int mloc = wm + mi * 16 + fq * 4;
#pragma unroll
    for (int ni = 0; ni < 4; ++ni) {
      int col = n0 + ni * 16 + fr;
#pragma unroll
      for (int r = 0; r < 4; ++r) {
        int mrow = mloc + r;
        if (mrow < mv)
          O[(size_t)(gbase + mrow) * DDIM + col] = f2bf(acc[mi][ni][r]);
      }
    }
  }
}

// ---------------- combine ----------------

__global__ void k_combine(const unsigned short* __restrict__ O, const int* __restrict__ bases,
                          const int* __restrict__ tok_slot, const float* __restrict__ wgt_list,
                          float* __restrict__ out) {
  int t = blockIdx.x;
  int s0 = tok_slot[t * 2 + 0];
  int s1 = tok_slot[t * 2 + 1];
  int g0 = bases[s0 / CAP] + (s0 & (CAP - 1));
  int g1 = bases[s1 / CAP] + (s1 & (CAP - 1));
  float w0 = wgt_list[s0], w1 = wgt_list[s1];
  int d = threadIdx.x * 4;
  ushort4 a = *(const ushort4*)(O + (size_t)g0 * DDIM + d);
  ushort4 b = *(const ushort4*)(O + (size_t)g1 * DDIM + d);
  float4 r;
  r.x = w0 * bf2f(a.x) + w1 * bf2f(b.x);
  r.y = w0 * bf2f(a.y) + w1 * bf2f(b.y);
  r.z = w0 * bf2f(a.z) + w1 * bf2f(b.z);
  r.w = w0 * bf2f(a.w) + w1 * bf2f(b.w);
  *(float4*)(out + (size_t)t * DDIM + d) = r;
}

// ---------------- launch ----------------

extern "C" void kernel_launch(void* const* d_in, const int* in_sizes, int n_in,
                              void* d_out, int out_size, void* d_ws, size_t ws_size,
                              hipStream_t stream) {
  const float* x   = (const float*)d_in[0];
  const float* gw  = (const float*)d_in[1];
  const float* wi0 = (const float*)d_in[2];
  const float* wi1 = (const float*)d_in[3];
  const float* wo  = (const float*)d_in[4];
  float* out = (float*)d_out;

  char* p = (char*)d_ws;
  unsigned short* xb  = (unsigned short*)p; p += (size_t)TOKENS * DDIM * 2;
  unsigned short* w0t = (unsigned short*)p; p += (size_t)NEXP * FDIM * DDIM * 2;
  unsigned short* w1t = (unsigned short*)p; p += (size_t)NEXP * FDIM * DDIM * 2;
  unsigned short* wot = (unsigned short*)p; p += (size_t)NEXP * DDIM * FDIM * 2;
  unsigned short* H   = (unsigned short*)p; p += (size_t)2 * TOKENS * FDIM * 2;
  unsigned short* O   = (unsigned short*)p; p += (size_t)2 * TOKENS * DDIM * 2;
  int*   counts   = (int*)p; p += 256;
  int*   bases    = (int*)p; p += 256;
  int*   tok_list = (int*)p; p += (size_t)NEXP * CAP * 4;
  float* wgt_list = (float*)p; p += (size_t)NEXP * CAP * 4;
  int*   tok_slot = (int*)p; p += (size_t)TOKENS * 2 * 4;

  // weight transpose+convert
  k_tconv<<<dim3(FDIM / 128, DDIM / 32, NEXP), 256, 0, stream>>>(wi0, w0t, DDIM, FDIM);
  k_tconv<<<dim3(FDIM / 128, DDIM / 32, NEXP), 256, 0, stream>>>(wi1, w1t, DDIM, FDIM);
  k_tconv<<<dim3(DDIM / 128, FDIM / 32, NEXP), 256, 0, stream>>>(wo, wot, FDIM, DDIM);

  // gating + routing (also emits xb)
  k_zero<<<1, 64, 0, stream>>>(counts);
  k_gate<<<TOKENS / 4, 256, 0, stream>>>(x, gw, xb, counts, tok_list, wgt_list, tok_slot);
  k_scan<<<1, 64, 0, stream>>>(counts, bases);

  // expert MLP (1D XCD-swizzled grids)
  k_gemm1<<<(FDIM / BN) * (CAP / BM) * NEXP, 256, 0, stream>>>(xb, w0t, w1t, counts, bases, tok_list, H);
  k_gemm2<<<(DDIM / BN) * (CAP / BM) * NEXP, 256, 0, stream>>>(H, wot, counts, bases, O);

  // weighted combine
  k_combine<<<TOKENS, 256, 0, stream>>>(O, bases, tok_slot, wgt_list, out);
}